// Round 10
// baseline (591.649 us; speedup 1.0000x reference)
//
#include <hip/hip_runtime.h>
#include <hip/hip_bf16.h>

// HGT layer: N=50000, E=400000, D=256, T=3, R=6, H=4, DK=64.
// Round 15: R14 with the vb-pointer bug FIXED (R14 computed vv from
// rp + 12,800,000 u16 = +25.6MB = qb, not vb; aggregated QUERY vectors
// -> absmax 1.72). Now vp is derived from the vb argument directly.
// Structure: fused online-softmax edge pass (one walk per (dst,r), kb+vb
// gathered concurrently, logit via 8-lane shfl, ex*v + denom in registers),
// r-loop in block, accF register accumulation, no atomics.

#define NN 50000
#define EE 400000
#define TN 3
#define RN 6
#define HN 4
#define SS (NN * RN)
#define NCHUNK 293   // ceil(SS/1024)
#define CD 16        // dsts per k2k4 block

typedef __hip_bfloat16 bf16;
typedef unsigned short u16;
using bf16x8 = __attribute__((ext_vector_type(8))) __bf16;
using f32x4  = __attribute__((ext_vector_type(4))) float;

__device__ __forceinline__ float b2f(bf16 h) { return __bfloat162float(h); }
__device__ __forceinline__ float busf(u16 u) { return __uint_as_float((unsigned)u << 16); }
__device__ __forceinline__ float blo(unsigned u) { return __uint_as_float(u << 16); }
__device__ __forceinline__ float bhi(unsigned u) { return __uint_as_float(u & 0xffff0000u); }
__device__ __forceinline__ u16 f2us(float f) {   // f32 -> bf16 bits, RNE
    unsigned u = __float_as_uint(f);
    return (u16)((u + 0x7fffu + ((u >> 16) & 1u)) >> 16);
}
__device__ __forceinline__ float ld(const void* p, long i, int f) {
    return f ? ((const float*)p)[i] : b2f(((const bf16*)p)[i]);
}

// ---------------- input dtype sniffer (f32 vs bf16 buffers) ----------------
__global__ __launch_bounds__(256) void detect_dtype(const void* __restrict__ x,
                                                    int* __restrict__ flag) {
    __shared__ int cnt_s;
    if (threadIdx.x == 0) cnt_s = 0;
    __syncthreads();
    const u16* p = (const u16*)x;
    int c = 0;
    for (int i = threadIdx.x; i < 8192; i += 256) {
        int expo = (p[i] >> 7) & 0xFF;
        if (expo >= 0x97) ++c;
    }
    atomicAdd(&cnt_s, c);
    __syncthreads();
    if (threadIdx.x == 0) *flag = (cnt_s > 64) ? 1 : 0;
}

// ---------------- merged prep: transM + transW + convertX + bucket + count ----------------
__global__ __launch_bounds__(256) void prep(const void* __restrict__ rel_att,
        const void* __restrict__ rel_msg,
        const void* __restrict__ Wk, const void* __restrict__ Wq,
        const void* __restrict__ Wv, const void* __restrict__ Wa,
        const void* __restrict__ x, const int* __restrict__ node_type,
        const int* __restrict__ edst, const int* __restrict__ etype,
        const int* __restrict__ flag,
        u16* __restrict__ MTa, u16* __restrict__ MTm,
        u16* __restrict__ WallT, u16* __restrict__ WaT,
        u16* __restrict__ xb,
        int* __restrict__ lists, int* __restrict__ cnts,
        unsigned* __restrict__ cnt) {
    int b = blockIdx.x;
    int t = threadIdx.x;
    if (b < 48) {
        int f = *flag;
        int m = b;                 // 0..23 att copy, 24..47 msg transpose
        long base = (long)(m % 24) * 4096;
        if (m < 24) {
            for (int it = 0; it < 16; ++it) {
                int idx = it * 256 + t;
                MTa[base + idx] = f2us(ld(rel_att, base + idx, f));
            }
        } else {
            for (int it = 0; it < 16; ++it) {
                int idx = it * 256 + t;
                int d = idx >> 6, j = idx & 63;
                MTm[base + (j << 6) + d] = f2us(ld(rel_msg, base + idx, f));
            }
        }
    } else if (b < 3120) {
        int f = *flag;
        int m = b - 48;            // 0..2303 WallT rows, 2304..3071 WaT rows
        if (m < 2304) {
            int ty = m / 768, o3 = m % 768;
            int sec = o3 >> 8, o = o3 & 255;
            const void* W = (sec == 0) ? Wk : (sec == 1) ? Wq : Wv;
            WallT[(size_t)ty * 768 * 256 + (size_t)o3 * 256 + t] =
                f2us(ld(W, (long)ty * 65536 + (long)t * 256 + o, f));
        } else {
            int mm = m - 2304;
            int ty = mm / 256, o = mm % 256;
            WaT[(size_t)ty * 65536 + (size_t)o * 256 + t] =
                f2us(ld(Wa, (long)ty * 65536 + (long)t * 256 + o, f));
        }
    } else if (b < 15620) {
        int f = *flag;
        long i = ((long)(b - 3120) * 256 + t) * 4;
        if (i < (long)NN * 256) {
            if (f) {
                float4 v = *(const float4*)((const float*)x + i);
                ushort4 p; p.x = f2us(v.x); p.y = f2us(v.y); p.z = f2us(v.z); p.w = f2us(v.w);
                *(ushort4*)(xb + i) = p;
            } else {
                *(ushort4*)(xb + i) = *(const ushort4*)((const u16*)x + i);
            }
        }
    } else if (b < 15816) {
        __shared__ int lc[TN], lbase[TN];
        if (t < TN) lc[t] = 0;
        __syncthreads();
        int n = (b - 15620) * 256 + t;
        int pos = -1, ty = 0;
        if (n < NN) {
            ty = node_type[n];
            pos = atomicAdd(&lc[ty], 1);
        }
        __syncthreads();
        if (t < TN) lbase[t] = atomicAdd(&cnts[t], lc[t]);
        __syncthreads();
        if (n < NN) lists[ty * NN + lbase[ty] + pos] = n;
    } else {
        int e = (b - 15816) * 256 + t;
        if (e < EE) atomicAdd(&cnt[etype[e] * NN + edst[e]], 1u);
    }
}

// ---------------- 3-phase exclusive scan over SS segments ----------------
__global__ __launch_bounds__(256) void scanA(const unsigned* __restrict__ cnt,
                                             unsigned* __restrict__ csums) {
    __shared__ unsigned s[256];
    int b = blockIdx.x, t = threadIdx.x;
    int s0 = b * 1024 + t * 4;
    unsigned v = 0;
    if (s0 + 3 < SS) { uint4 u = *(const uint4*)&cnt[s0]; v = u.x + u.y + u.z + u.w; }
    else { for (int j = 0; j < 4; ++j) if (s0 + j < SS) v += cnt[s0 + j]; }
    s[t] = v;
    __syncthreads();
    for (int st = 128; st > 0; st >>= 1) {
        if (t < st) s[t] += s[t + st];
        __syncthreads();
    }
    if (t == 0) csums[b] = s[0];
}

__global__ __launch_bounds__(256) void scanB(unsigned* __restrict__ csums,
                                             int* __restrict__ base) {
    __shared__ unsigned s[512];
    int t = threadIdx.x;
    unsigned a = (t < NCHUNK) ? csums[t] : 0u;
    unsigned b = (256 + t < NCHUNK) ? csums[256 + t] : 0u;
    s[t] = a; s[256 + t] = b;
    __syncthreads();
    for (int st = 1; st < 512; st <<= 1) {
        unsigned x0 = (t >= st) ? s[t - st] : 0u;
        unsigned x1 = (256 + t >= st) ? s[256 + t - st] : 0u;
        __syncthreads();
        s[t] += x0; s[256 + t] += x1;
        __syncthreads();
    }
    if (t < NCHUNK) csums[t] = s[t] - a;
    if (256 + t < NCHUNK) csums[256 + t] = s[256 + t] - b;
    if (t == 0) base[SS] = (int)s[NCHUNK - 1];
}

__global__ __launch_bounds__(256) void scanC(const unsigned* __restrict__ cnt,
        const unsigned* __restrict__ csums, int* __restrict__ base) {
    __shared__ unsigned s[256];
    int b = blockIdx.x, t = threadIdx.x;
    int s0 = b * 1024 + t * 4;
    unsigned vs[4] = {0u, 0u, 0u, 0u};
    if (s0 + 3 < SS) { uint4 u = *(const uint4*)&cnt[s0]; vs[0]=u.x; vs[1]=u.y; vs[2]=u.z; vs[3]=u.w; }
    else { for (int j = 0; j < 4; ++j) if (s0 + j < SS) vs[j] = cnt[s0 + j]; }
    unsigned v = vs[0] + vs[1] + vs[2] + vs[3];
    s[t] = v;
    __syncthreads();
    for (int st = 1; st < 256; st <<= 1) {
        unsigned x = (t >= st) ? s[t - st] : 0u;
        __syncthreads();
        s[t] += x;
        __syncthreads();
    }
    unsigned run = csums[b] + s[t] - v;
    for (int j = 0; j < 4; ++j) {
        if (s0 + j < SS) { base[s0 + j] = (int)run; run += vs[j]; }
    }
}

// ---------------- scatter edges into seg-sorted order (consumes cnt) ----------------
__global__ __launch_bounds__(256) void scatter_edges(const int* __restrict__ edst,
        const int* __restrict__ etype, const int* __restrict__ base,
        unsigned* __restrict__ cnt, int* __restrict__ sorted) {
    int e = blockIdx.x * 256 + threadIdx.x;
    if (e >= EE) return;
    int seg = etype[e] * NN + edst[e];
    unsigned old = atomicSub(&cnt[seg], 1u);
    sorted[base[seg] + (int)old - 1] = e;
}

// ---------------- k/q/v typed linear via MFMA (64 same-type nodes / block) ----------------
__global__ __launch_bounds__(512, 2) void k1_mfma(const u16* __restrict__ xb,
        const u16* __restrict__ WallT,
        const void* __restrict__ bk, const void* __restrict__ bq,
        const void* __restrict__ bv,
        const int* __restrict__ lists, const int* __restrict__ cnts,
        const int* __restrict__ flag,
        u16* __restrict__ kb, u16* __restrict__ qb, u16* __restrict__ vb) {
    int f = *flag;
    int tt = blockIdx.x % TN, tile = blockIdx.x / TN;
    int cnt = cnts[tt];
    int start = tile * 64;
    if (start >= cnt) return;
    __shared__ int nl[64];
    __shared__ __align__(16) u16 xs[64][280];
    __shared__ __align__(16) float bias_s[768];
    int t = threadIdx.x;
    if (t < 64) nl[t] = (start + t < cnt) ? lists[tt * NN + start + t] : -1;
    if (t < 256) {
        bias_s[t]       = ld(bk, tt * 256 + t, f);
        bias_s[256 + t] = ld(bq, tt * 256 + t, f);
        bias_s[512 + t] = ld(bv, tt * 256 + t, f);
    }
    __syncthreads();
    {
        int i = t >> 4, g = t & 15;
        #pragma unroll
        for (int i2 = 0; i2 < 2; ++i2) {
            int row = i + i2 * 32;
            int node = nl[row];
            uint4 a = {0, 0, 0, 0}, b = {0, 0, 0, 0};
            if (node >= 0) {
                const uint4* src = (const uint4*)(xb + (size_t)node * 256 + g * 16);
                a = src[0]; b = src[1];
            }
            *(uint4*)&xs[row][g * 16] = a;
            *(uint4*)&xs[row][g * 16 + 8] = b;
        }
    }
    __syncthreads();
    int w = t >> 6, lane = t & 63, ln = lane & 15, quad = lane >> 4;
    const u16* Wt = WallT + (size_t)tt * 768 * 256;
    f32x4 acc[6][4];
    #pragma unroll
    for (int j = 0; j < 6; ++j)
        #pragma unroll
        for (int g = 0; g < 4; ++g)
            acc[j][g] = (f32x4){0.f, 0.f, 0.f, 0.f};
    for (int kt = 0; kt < 8; ++kt) {
        bf16x8 A[6];
        #pragma unroll
        for (int jt = 0; jt < 6; ++jt)
            A[jt] = *(const bf16x8*)(Wt + (size_t)(w * 96 + jt * 16 + ln) * 256 + kt * 32 + quad * 8);
        bf16x8 B[4];
        #pragma unroll
        for (int g = 0; g < 4; ++g)
            B[g] = *(const bf16x8*)&xs[g * 16 + ln][kt * 32 + quad * 8];
        #pragma unroll
        for (int jt = 0; jt < 6; ++jt)
            #pragma unroll
            for (int g = 0; g < 4; ++g)
                acc[jt][g] = __builtin_amdgcn_mfma_f32_16x16x32_bf16(A[jt], B[g], acc[jt][g], 0, 0, 0);
    }
    #pragma unroll
    for (int jt = 0; jt < 6; ++jt) {
        int jc = w * 96 + jt * 16 + quad * 4;
        float4 bi = *(const float4*)&bias_s[jc];
        int sec = jc >> 8, o = jc & 255;
        u16* basep = (sec == 0 ? kb : sec == 1 ? qb : vb);
        #pragma unroll
        for (int g = 0; g < 4; ++g) {
            int node = nl[g * 16 + ln];
            if (node >= 0) {
                ushort4 p;
                p.x = f2us(acc[jt][g][0] + bi.x); p.y = f2us(acc[jt][g][1] + bi.y);
                p.z = f2us(acc[jt][g][2] + bi.z); p.w = f2us(acc[jt][g][3] + bi.w);
                *(ushort4*)(basep + (size_t)node * 256 + o) = p;
            }
        }
    }
}

// ---------------- fused attention + aggregation, r-loop in block ----------------
// grid NN/CD = 3125; block = 16 consecutive dsts, loops r=0..5.
// Per r: qrelL = MTa[r] @ qL (MFMA) -> sync -> fused edge pass (half-wave
// per dst: kb+vb gathered concurrently per edge, logit via 8-lane shfl
// reduce, ex*v + denom accumulated in REGISTERS, normalized once) -> sync
// -> accF += MTm[r] @ sraw (register accumulation). One tacc store at end.
__global__ __launch_bounds__(256) void k2k4(const u16* __restrict__ kb,
        const u16* __restrict__ qb, const u16* __restrict__ vb,
        const u16* __restrict__ MTa, const u16* __restrict__ MTm,
        const void* __restrict__ rel_pri,
        const int* __restrict__ sorted, const int* __restrict__ base,
        const int* __restrict__ esrc,
        const int* __restrict__ flag, float* __restrict__ tacc) {
    int f = *flag;
    int c0 = blockIdx.x * CD;
    int nd = min(CD, NN - c0);       // always 16 (50000 = 3125*16)
    __shared__ int sb_[CD + 1];
    __shared__ __align__(16) u16 qL[CD][264];
    __shared__ __align__(16) u16 qrelL[CD][264];
    __shared__ __align__(16) u16 srawL[CD][264];
    int t = threadIdx.x;
    int w = t >> 6, lane = t & 63, ln = lane & 15, quad = lane >> 4;
    int half = lane >> 5, lane32 = lane & 31;
    int hh = lane32 >> 3;            // head for the fused pass (8 lanes/head)
    // stage q rows ONCE (16 threads per row, 32B each)
    {
        int i = t >> 4, g = t & 15;
        uint4 a0 = {0,0,0,0}, a1 = {0,0,0,0};
        if (i < nd) {
            const uint4* src = (const uint4*)(qb + (size_t)(c0 + i) * 256 + g * 16);
            a0 = src[0]; a1 = src[1];
        }
        *(uint4*)&qL[i][g * 16] = a0;
        *(uint4*)&qL[i][g * 16 + 8] = a1;
    }
    f32x4 accF[4];
    #pragma unroll
    for (int m = 0; m < 4; ++m) accF[m] = (f32x4){0.f, 0.f, 0.f, 0.f};

    for (int r = 0; r < RN; ++r) {
        if (t <= nd) sb_[t] = base[r * NN + c0 + t];
        __syncthreads();   // S1: sb ready; prev phase C done with srawL; qL staged (r=0)
        long mtbase = (long)(r * HN + w) * 4096;
        // phase 0.5: qrelL = MTa[r] @ qL   (wave = head, rows = ln)
        {
            bf16x8 B0 = *(const bf16x8*)&qL[ln][w * 64 + quad * 8];
            bf16x8 B1 = *(const bf16x8*)&qL[ln][w * 64 + quad * 8 + 32];
            #pragma unroll
            for (int mt = 0; mt < 4; ++mt) {
                const u16* ap = MTa + mtbase + (mt * 16 + ln) * 64 + quad * 8;
                bf16x8 A0 = *(const bf16x8*)(ap);
                bf16x8 A1 = *(const bf16x8*)(ap + 32);
                f32x4 acc = {0.f, 0.f, 0.f, 0.f};
                acc = __builtin_amdgcn_mfma_f32_16x16x32_bf16(A0, B0, acc, 0, 0, 0);
                acc = __builtin_amdgcn_mfma_f32_16x16x32_bf16(A1, B1, acc, 0, 0, 0);
                int jc = w * 64 + mt * 16 + quad * 4;
                ushort4 pq;
                pq.x = f2us(acc[0]); pq.y = f2us(acc[1]);
                pq.z = f2us(acc[2]); pq.w = f2us(acc[3]);
                *(ushort4*)&qrelL[ln][jc] = pq;
            }
        }
        __syncthreads();   // S2: qrel ready
        // fused phase AB: half-wave per dst; 8 dims/lane; online softmax.
        {
            float pri = ld(rel_pri, r * HN + hh, f) * 0.125f;
            for (int i2 = w * 2 + half; i2 < nd; i2 += 8) {
                int sb = sb_[i2], se = sb_[i2 + 1];
                float a0=0.f,a1=0.f,a2=0.f,a3=0.f,a4=0.f,a5=0.f,a6=0.f,a7=0.f;
                if (se > sb) {
                    uint4 qv = *(const uint4*)&qrelL[i2][lane32 * 8];
                    float q0=blo(qv.x),q1=bhi(qv.x),q2=blo(qv.y),q3=bhi(qv.y);
                    float q4=blo(qv.z),q5=bhi(qv.z),q6=blo(qv.w),q7=bhi(qv.w);
                    float den = 0.f;
                    for (int idx = sb; idx < se; ++idx) {
                        int e = sorted[idx];
                        int s = esrc[e];
                        size_t rowoff = (size_t)s * 256 + lane32 * 8;
                        uint4 kv = *(const uint4*)(kb + rowoff);
                        uint4 vv = *(const uint4*)(vb + rowoff);
                        float d = blo(kv.x)*q0 + bhi(kv.x)*q1 + blo(kv.y)*q2 + bhi(kv.y)*q3
                                + blo(kv.z)*q4 + bhi(kv.z)*q5 + blo(kv.w)*q6 + bhi(kv.w)*q7;
                        d += __shfl_xor(d, 1); d += __shfl_xor(d, 2); d += __shfl_xor(d, 4);
                        float attv = fminf(fmaxf(d * pri, -50.f), 50.f);
                        float ex = expf(attv);
                        den += ex;
                        a0 += ex * blo(vv.x); a1 += ex * bhi(vv.x);
                        a2 += ex * blo(vv.y); a3 += ex * bhi(vv.y);
                        a4 += ex * blo(vv.z); a5 += ex * bhi(vv.z);
                        a6 += ex * blo(vv.w); a7 += ex * bhi(vv.w);
                    }
                    float inv = 1.f / den;
                    a0 *= inv; a1 *= inv; a2 *= inv; a3 *= inv;
                    a4 *= inv; a5 *= inv; a6 *= inv; a7 *= inv;
                }
                u16 pv8[8];
                pv8[0]=f2us(a0); pv8[1]=f2us(a1); pv8[2]=f2us(a2); pv8[3]=f2us(a3);
                pv8[4]=f2us(a4); pv8[5]=f2us(a5); pv8[6]=f2us(a6); pv8[7]=f2us(a7);
                *(uint4*)&srawL[i2][lane32 * 8] = *(const uint4*)pv8;
            }
        }
        __syncthreads();   // S3: sraw ready
        // phase C: accF += MTm[r] @ sraw  (register accumulation across r)
        {
            bf16x8 B0 = *(const bf16x8*)&srawL[ln][w * 64 + quad * 8];
            bf16x8 B1 = *(const bf16x8*)&srawL[ln][w * 64 + quad * 8 + 32];
            #pragma unroll
            for (int mt = 0; mt < 4; ++mt) {
                const u16* mp = MTm + mtbase + (mt * 16 + ln) * 64 + quad * 8;
                bf16x8 A0 = *(const bf16x8*)(mp);
                bf16x8 A1 = *(const bf16x8*)(mp + 32);
                accF[mt] = __builtin_amdgcn_mfma_f32_16x16x32_bf16(A0, B0, accF[mt], 0, 0, 0);
                accF[mt] = __builtin_amdgcn_mfma_f32_16x16x32_bf16(A1, B1, accF[mt], 0, 0, 0);
            }
        }
        // next iteration's S1 separates phase C reads from next writes
    }
    // single tacc write (f32, no atomics)
    if (ln < nd) {
        #pragma unroll
        for (int mt = 0; mt < 4; ++mt) {
            int jc = w * 64 + mt * 16 + quad * 4;
            float4 v = {accF[mt][0], accF[mt][1], accF[mt][2], accF[mt][3]};
            *(float4*)(tacc + (long)(c0 + ln) * 256 + jc) = v;
        }
    }
}

// ---------------- fused out-linear (MFMA) + skip-gate + LayerNorm ----------------
__global__ __launch_bounds__(512, 4) void k5_fused(const void* __restrict__ x,
        const float* __restrict__ tacc, const u16* __restrict__ WaT,
        const void* __restrict__ ba, const void* __restrict__ skip,
        const void* __restrict__ ln_g, const void* __restrict__ ln_b,
        const int* __restrict__ base,
        const int* __restrict__ lists, const int* __restrict__ cnts,
        const int* __restrict__ flag, void* out) {
    int f = *flag;
    int tt = blockIdx.x % TN, tile = blockIdx.x / TN;
    int cnt = cnts[tt];
    int start = tile * 64;
    if (start >= cnt) return;
    __shared__ int nl[64];
    __shared__ float invs[64];
    __shared__ int hasv[64];
    __shared__ __align__(16) u16 xs[64][280];
    __shared__ __align__(16) float ba_s[256], lnG_s[256], lnB_s[256];
    __shared__ float red1[64][8], red2[64][8];
    __shared__ float mu_[64], rs_[64];
    int t = threadIdx.x;
    if (t < 64) {
        int node = (start + t < cnt) ? lists[tt * NN + start + t] : -1;
        nl[t] = node;
        int nrel = 0;
        if (node >= 0) {
            #pragma unroll
            for (int r = 0; r < RN; ++r)
                nrel += (base[r * NN + node + 1] > base[r * NN + node]) ? 1 : 0;
        }
        hasv[t] = nrel;
        invs[t] = (nrel > 0) ? 1.f / (float)nrel : 1.f;
    }
    if (t < 256) {
        ba_s[t]  = ld(ba,   tt * 256 + t, f);
        lnG_s[t] = ld(ln_g, tt * 256 + t, f);
        lnB_s[t] = ld(ln_b, tt * 256 + t, f);
    }
    __syncthreads();
    // gather tacc (f32) -> xs (bf16, pre-divided by nrel), vectorized
    {
        int i = t >> 3, g8 = t & 7;
        int node = nl[i];
        float inv = invs[i];
        int o0 = g8 * 32;
        u16 tmp[32];
        if (node >= 0) {
            const float* src = tacc + (long)node * 256 + o0;
            #pragma unroll
            for (int j = 0; j < 8; ++j) {
                float4 v = *(const float4*)(src + j * 4);
                tmp[j*4+0] = f2us(v.x * inv); tmp[j*4+1] = f2us(v.y * inv);
                tmp[j*4+2] = f2us(v.z * inv); tmp[j*4+3] = f2us(v.w * inv);
            }
        } else {
            #pragma unroll
            for (int j = 0; j < 32; ++j) tmp[j] = 0;
        }
        #pragma unroll
        for (int j = 0; j < 4; ++j)
            *(uint4*)&xs[i][o0 + j * 8] = ((const uint4*)tmp)[j];
    }
    __syncthreads();
    int w = t >> 6, lane = t & 63, ln = lane & 15, quad = lane >> 4;
    const u16* Wt = WaT + (size_t)tt * 65536;
    f32x4 acc[2][4];
    #pragma unroll
    for (int j = 0; j < 2; ++j)
        #pragma unroll
        for (int g = 0; g < 4; ++g)
            acc[j][g] = (f32x4){0.f, 0.f, 0.f, 0.f};
    for (int kt = 0; kt < 8; ++kt) {
        bf16x8 A[2];
        #pragma unroll
        for (int jt = 0; jt < 2; ++jt)
            A[jt] = *(const bf16x8*)(Wt + (size_t)(w * 32 + jt * 16 + ln) * 256 + kt * 32 + quad * 8);
        bf16x8 B[4];
        #pragma unroll
        for (int g = 0; g < 4; ++g)
            B[g] = *(const bf16x8*)&xs[g * 16 + ln][kt * 32 + quad * 8];
        #pragma unroll
        for (int jt = 0; jt < 2; ++jt)
            #pragma unroll
            for (int g = 0; g < 4; ++g)
                acc[jt][g] = __builtin_amdgcn_mfma_f32_16x16x32_bf16(A[jt], B[g], acc[jt][g], 0, 0, 0);
    }
    float sk = ld(skip, tt, f);
    float alpha = 1.f / (1.f + expf(-sk));
    float p1[4] = {0.f, 0.f, 0.f, 0.f}, p2[4] = {0.f, 0.f, 0.f, 0.f};
    #pragma unroll
    for (int g = 0; g < 4; ++g) {
        int node = nl[g * 16 + ln];
        if (node < 0) continue;
        #pragma unroll
        for (int jt = 0; jt < 2; ++jt) {
            int jc = w * 32 + jt * 16 + quad * 4;
            float4 bi = *(const float4*)&ba_s[jc];
            long xo = (long)node * 256 + jc;
            float xv[4];
            if (f) {
                float4 v = *(const float4*)((const float*)x + xo);
                xv[0] = v.x; xv[1] = v.y; xv[2] = v.z; xv[3] = v.w;
            } else {
                ushort4 v = *(const ushort4*)((const u16*)x + xo);
                xv[0] = busf(v.x); xv[1] = busf(v.y); xv[2] = busf(v.z); xv[3] = busf(v.w);
            }
            #pragma unroll
            for (int rg = 0; rg < 4; ++rg) {
                float ov = acc[jt][g][rg] + ((const float*)&bi)[rg];
                ov = ov * alpha + xv[rg] * (1.f - alpha);
                acc[jt][g][rg] = ov;
                p1[g] += ov; p2[g] += ov * ov;
            }
        }
    }
    #pragma unroll
    for (int g = 0; g < 4; ++g) {
        p1[g] += __shfl_xor(p1[g], 16); p1[g] += __shfl_xor(p1[g], 32);
        p2[g] += __shfl_xor(p2[g], 16); p2[g] += __shfl_xor(p2[g], 32);
    }
    if (quad == 0) {
        #pragma unroll
        for (int g = 0; g < 4; ++g) {
            red1[g * 16 + ln][w] = p1[g];
            red2[g * 16 + ln][w] = p2[g];
        }
    }
    __syncthreads();
    if (t < 64) {
        float s1 = 0.f, s2 = 0.f;
        #pragma unroll
        for (int j = 0; j < 8; ++j) { s1 += red1[t][j]; s2 += red2[t][j]; }
        float mu = s1 * (1.f / 256.f);
        float ms = s2 * (1.f / 256.f);
        float var = fmaxf(ms - mu * mu, 0.f);
        mu_[t] = mu; rs_[t] = rsqrtf(var + 1e-5f);
    }
    __syncthreads();
    #pragma unroll
    for (int g = 0; g < 4; ++g) {
        int li = g * 16 + ln;
        int node = nl[li];
        if (node < 0) continue;
        if (hasv[li] > 0) {
            float mu = mu_[li], rs = rs_[li];
            #pragma unroll
            for (int jt = 0; jt < 2; ++jt) {
                int jc = w * 32 + jt * 16 + quad * 4;
                float4 gg = *(const float4*)&lnG_s[jc];
                float4 bb = *(const float4*)&lnB_s[jc];
                long oo = (long)node * 256 + jc;
                float r0 = (acc[jt][g][0] - mu) * rs * gg.x + bb.x;
                float r1 = (acc[jt][g][1] - mu) * rs * gg.y + bb.y;
                float r2 = (acc[jt][g][2] - mu) * rs * gg.z + bb.z;
                float r3 = (acc[jt][g][3] - mu) * rs * gg.w + bb.w;
                if (f) { float4 v = {r0, r1, r2, r3}; *(float4*)((float*)out + oo) = v; }
                else   { ushort4 v; v.x = f2us(r0); v.y = f2us(r1); v.z = f2us(r2); v.w = f2us(r3);
                         *(ushort4*)((u16*)out + oo) = v; }
            }
        } else {
            #pragma unroll
            for (int jt = 0; jt < 2; ++jt) {
                int jc = w * 32 + jt * 16 + quad * 4;
                long oo = (long)node * 256 + jc;
                if (f) { *(float4*)((float*)out + oo) = *(const float4*)((const float*)x + oo); }
                else   { *(ushort4*)((u16*)out + oo) = *(const ushort4*)((const u16*)x + oo); }
            }
        }
    }
}

extern "C" void kernel_launch(void* const* d_in, const int* in_sizes, int n_in,
                              void* d_out, int out_size, void* d_ws, size_t ws_size,
                              hipStream_t stream) {
    const void* x       = d_in[0];
    const void* Wk      = d_in[1];
    const void* bk      = d_in[2];
    const void* Wq      = d_in[3];
    const void* bq      = d_in[4];
    const void* Wv      = d_in[5];
    const void* bv      = d_in[6];
    const void* Wa      = d_in[7];
    const void* ba      = d_in[8];
    const void* rel_pri = d_in[9];
    const void* rel_att = d_in[10];
    const void* rel_msg = d_in[11];
    const void* skip    = d_in[12];
    const void* ln_g    = d_in[13];
    const void* ln_b    = d_in[14];
    const int* node_type = (const int*)d_in[15];
    const int* edge_src  = (const int*)d_in[16];
    const int* edge_dst  = (const int*)d_in[17];
    const int* edge_type = (const int*)d_in[18];
    char* w = (char*)d_ws;

    // layout (bytes) — total 137,767,552 <= proven ws floor 141,000,128
    u16*      kb     = (u16*)(w);                    // 25,600,000
    u16*      qb     = (u16*)(w + 25600000);         // 25,600,000
    u16*      vb     = (u16*)(w + 51200000);         // 25,600,000
    float*    tacc   = (float*)(w + 76800000);       // 51,200,000 (f32; xb overlay first)
    u16*      xb     = (u16*)(w + 76800000);         //   overlay (consumed by k1)
    u16*      attex  = (u16*)(w + 128000000);        //  3,200,000 (unused since R14)
    int*      sorted = (int*)(w + 131200000);        //  1,600,000
    int*      base   = (int*)(w + 132800000);        //  1,200,064
    int*      nlists = (int*)(w + 134000064);        //    600,000
    u16*      MTa    = (u16*)(w + 134600064);        //    196,608
    u16*      MTm    = (u16*)(w + 134796672);        //    196,608
    u16*      WallT  = (u16*)(w + 134993280);        //  1,179,648
    u16*      WaT    = (u16*)(w + 136172928);        //    393,216
    // zero region:
    unsigned* cnt    = (unsigned*)(w + 136566144);   //  1,200,000
    int*      ncnts  = (int*)(w + 137766144);        //         64
    int*      flag   = (int*)(w + 137766208);        //         64
    unsigned* csums  = (unsigned*)(w + 137766272);   //      1,280
    (void)attex;

    hipMemsetAsync(w + 136566144, 0, 1201408, stream);

    detect_dtype<<<dim3(1), dim3(256), 0, stream>>>(x, flag);
    prep<<<dim3(17379), dim3(256), 0, stream>>>(
        rel_att, rel_msg, Wk, Wq, Wv, Wa, x, node_type, edge_dst, edge_type,
        flag, MTa, MTm, WallT, WaT, xb, nlists, ncnts, cnt);
    scanA<<<dim3(NCHUNK), dim3(256), 0, stream>>>(cnt, csums);
    scanB<<<dim3(1), dim3(256), 0, stream>>>(csums, base);
    scanC<<<dim3(NCHUNK), dim3(256), 0, stream>>>(cnt, csums, base);
    scatter_edges<<<dim3((EE + 255) / 256), dim3(256), 0, stream>>>(
        edge_dst, edge_type, base, cnt, sorted);

    k1_mfma<<<dim3(TN * ((NN + 63) / 64)), dim3(512), 0, stream>>>(
        xb, WallT, bk, bq, bv, nlists, ncnts, flag, kb, qb, vb);

    // tacc fully overwritten by k2k4 (register accumulation) -> no memset

    k2k4<<<dim3(NN / CD), dim3(256), 0, stream>>>(
        kb, qb, vb, MTa, MTm, rel_pri, sorted, base, edge_src,
        flag, tacc);

    k5_fused<<<dim3(TN * ((NN + 63) / 64)), dim3(512), 0, stream>>>(
        x, tacc, WaT, ba, skip, ln_g, ln_b, base, nlists, ncnts, flag, d_out);
}

// Round 11
// 553.928 us; speedup vs baseline: 1.0681x; 1.0681x over previous
//
#include <hip/hip_runtime.h>
#include <hip/hip_bf16.h>

// HGT layer: N=50000, E=400000, D=256, T=3, R=6, H=4, DK=64.
// Round 16: k2k4 gather-concurrency push. R15 post-mortem: 3 structures all
// plateau ~0.85 TB/s effective gather BW; bursts too short (1.33 edges per
// (dst,r)), waves idle at syncs/MFMA with no loads in flight. Changes:
//  - sorted[] now holds esrc[e] (written by scatter) -> edge chain loses one
//    dependent random load; k2k4 drops esrc entirely.
//  - dual-dst interleaved edge loop per half-wave (4 row loads in flight).
//  - sb2_[6][17] preloaded once; accF(r)+qrel(r+1) merged -> 14 syncs vs 18.
// Kept: fused online softmax, r-loop in block, accF register accumulation.

#define NN 50000
#define EE 400000
#define TN 3
#define RN 6
#define HN 4
#define SS (NN * RN)
#define NCHUNK 293   // ceil(SS/1024)
#define CD 16        // dsts per k2k4 block

typedef __hip_bfloat16 bf16;
typedef unsigned short u16;
using bf16x8 = __attribute__((ext_vector_type(8))) __bf16;
using f32x4  = __attribute__((ext_vector_type(4))) float;

__device__ __forceinline__ float b2f(bf16 h) { return __bfloat162float(h); }
__device__ __forceinline__ float busf(u16 u) { return __uint_as_float((unsigned)u << 16); }
__device__ __forceinline__ float blo(unsigned u) { return __uint_as_float(u << 16); }
__device__ __forceinline__ float bhi(unsigned u) { return __uint_as_float(u & 0xffff0000u); }
__device__ __forceinline__ u16 f2us(float f) {   // f32 -> bf16 bits, RNE
    unsigned u = __float_as_uint(f);
    return (u16)((u + 0x7fffu + ((u >> 16) & 1u)) >> 16);
}
__device__ __forceinline__ float ld(const void* p, long i, int f) {
    return f ? ((const float*)p)[i] : b2f(((const bf16*)p)[i]);
}

// ---------------- input dtype sniffer (f32 vs bf16 buffers) ----------------
__global__ __launch_bounds__(256) void detect_dtype(const void* __restrict__ x,
                                                    int* __restrict__ flag) {
    __shared__ int cnt_s;
    if (threadIdx.x == 0) cnt_s = 0;
    __syncthreads();
    const u16* p = (const u16*)x;
    int c = 0;
    for (int i = threadIdx.x; i < 8192; i += 256) {
        int expo = (p[i] >> 7) & 0xFF;
        if (expo >= 0x97) ++c;
    }
    atomicAdd(&cnt_s, c);
    __syncthreads();
    if (threadIdx.x == 0) *flag = (cnt_s > 64) ? 1 : 0;
}

// ---------------- merged prep: transM + transW + convertX + bucket + count ----------------
__global__ __launch_bounds__(256) void prep(const void* __restrict__ rel_att,
        const void* __restrict__ rel_msg,
        const void* __restrict__ Wk, const void* __restrict__ Wq,
        const void* __restrict__ Wv, const void* __restrict__ Wa,
        const void* __restrict__ x, const int* __restrict__ node_type,
        const int* __restrict__ edst, const int* __restrict__ etype,
        const int* __restrict__ flag,
        u16* __restrict__ MTa, u16* __restrict__ MTm,
        u16* __restrict__ WallT, u16* __restrict__ WaT,
        u16* __restrict__ xb,
        int* __restrict__ lists, int* __restrict__ cnts,
        unsigned* __restrict__ cnt) {
    int b = blockIdx.x;
    int t = threadIdx.x;
    if (b < 48) {
        int f = *flag;
        int m = b;                 // 0..23 att copy, 24..47 msg transpose
        long base = (long)(m % 24) * 4096;
        if (m < 24) {
            for (int it = 0; it < 16; ++it) {
                int idx = it * 256 + t;
                MTa[base + idx] = f2us(ld(rel_att, base + idx, f));
            }
        } else {
            for (int it = 0; it < 16; ++it) {
                int idx = it * 256 + t;
                int d = idx >> 6, j = idx & 63;
                MTm[base + (j << 6) + d] = f2us(ld(rel_msg, base + idx, f));
            }
        }
    } else if (b < 3120) {
        int f = *flag;
        int m = b - 48;            // 0..2303 WallT rows, 2304..3071 WaT rows
        if (m < 2304) {
            int ty = m / 768, o3 = m % 768;
            int sec = o3 >> 8, o = o3 & 255;
            const void* W = (sec == 0) ? Wk : (sec == 1) ? Wq : Wv;
            WallT[(size_t)ty * 768 * 256 + (size_t)o3 * 256 + t] =
                f2us(ld(W, (long)ty * 65536 + (long)t * 256 + o, f));
        } else {
            int mm = m - 2304;
            int ty = mm / 256, o = mm % 256;
            WaT[(size_t)ty * 65536 + (size_t)o * 256 + t] =
                f2us(ld(Wa, (long)ty * 65536 + (long)t * 256 + o, f));
        }
    } else if (b < 15620) {
        int f = *flag;
        long i = ((long)(b - 3120) * 256 + t) * 4;
        if (i < (long)NN * 256) {
            if (f) {
                float4 v = *(const float4*)((const float*)x + i);
                ushort4 p; p.x = f2us(v.x); p.y = f2us(v.y); p.z = f2us(v.z); p.w = f2us(v.w);
                *(ushort4*)(xb + i) = p;
            } else {
                *(ushort4*)(xb + i) = *(const ushort4*)((const u16*)x + i);
            }
        }
    } else if (b < 15816) {
        __shared__ int lc[TN], lbase[TN];
        if (t < TN) lc[t] = 0;
        __syncthreads();
        int n = (b - 15620) * 256 + t;
        int pos = -1, ty = 0;
        if (n < NN) {
            ty = node_type[n];
            pos = atomicAdd(&lc[ty], 1);
        }
        __syncthreads();
        if (t < TN) lbase[t] = atomicAdd(&cnts[t], lc[t]);
        __syncthreads();
        if (n < NN) lists[ty * NN + lbase[ty] + pos] = n;
    } else {
        int e = (b - 15816) * 256 + t;
        if (e < EE) atomicAdd(&cnt[etype[e] * NN + edst[e]], 1u);
    }
}

// ---------------- 3-phase exclusive scan over SS segments ----------------
__global__ __launch_bounds__(256) void scanA(const unsigned* __restrict__ cnt,
                                             unsigned* __restrict__ csums) {
    __shared__ unsigned s[256];
    int b = blockIdx.x, t = threadIdx.x;
    int s0 = b * 1024 + t * 4;
    unsigned v = 0;
    if (s0 + 3 < SS) { uint4 u = *(const uint4*)&cnt[s0]; v = u.x + u.y + u.z + u.w; }
    else { for (int j = 0; j < 4; ++j) if (s0 + j < SS) v += cnt[s0 + j]; }
    s[t] = v;
    __syncthreads();
    for (int st = 128; st > 0; st >>= 1) {
        if (t < st) s[t] += s[t + st];
        __syncthreads();
    }
    if (t == 0) csums[b] = s[0];
}

__global__ __launch_bounds__(256) void scanB(unsigned* __restrict__ csums,
                                             int* __restrict__ base) {
    __shared__ unsigned s[512];
    int t = threadIdx.x;
    unsigned a = (t < NCHUNK) ? csums[t] : 0u;
    unsigned b = (256 + t < NCHUNK) ? csums[256 + t] : 0u;
    s[t] = a; s[256 + t] = b;
    __syncthreads();
    for (int st = 1; st < 512; st <<= 1) {
        unsigned x0 = (t >= st) ? s[t - st] : 0u;
        unsigned x1 = (256 + t >= st) ? s[256 + t - st] : 0u;
        __syncthreads();
        s[t] += x0; s[256 + t] += x1;
        __syncthreads();
    }
    if (t < NCHUNK) csums[t] = s[t] - a;
    if (256 + t < NCHUNK) csums[256 + t] = s[256 + t] - b;
    if (t == 0) base[SS] = (int)s[NCHUNK - 1];
}

__global__ __launch_bounds__(256) void scanC(const unsigned* __restrict__ cnt,
        const unsigned* __restrict__ csums, int* __restrict__ base) {
    __shared__ unsigned s[256];
    int b = blockIdx.x, t = threadIdx.x;
    int s0 = b * 1024 + t * 4;
    unsigned vs[4] = {0u, 0u, 0u, 0u};
    if (s0 + 3 < SS) { uint4 u = *(const uint4*)&cnt[s0]; vs[0]=u.x; vs[1]=u.y; vs[2]=u.z; vs[3]=u.w; }
    else { for (int j = 0; j < 4; ++j) if (s0 + j < SS) vs[j] = cnt[s0 + j]; }
    unsigned v = vs[0] + vs[1] + vs[2] + vs[3];
    s[t] = v;
    __syncthreads();
    for (int st = 1; st < 256; st <<= 1) {
        unsigned x = (t >= st) ? s[t - st] : 0u;
        __syncthreads();
        s[t] += x;
        __syncthreads();
    }
    unsigned run = csums[b] + s[t] - v;
    for (int j = 0; j < 4; ++j) {
        if (s0 + j < SS) { base[s0 + j] = (int)run; run += vs[j]; }
    }
}

// ---------------- scatter edges: sorted[] holds SRC node ids ----------------
__global__ __launch_bounds__(256) void scatter_edges(const int* __restrict__ edst,
        const int* __restrict__ etype, const int* __restrict__ esrc,
        const int* __restrict__ base,
        unsigned* __restrict__ cnt, int* __restrict__ sorted) {
    int e = blockIdx.x * 256 + threadIdx.x;
    if (e >= EE) return;
    int seg = etype[e] * NN + edst[e];
    unsigned old = atomicSub(&cnt[seg], 1u);
    sorted[base[seg] + (int)old - 1] = esrc[e];
}

// ---------------- k/q/v typed linear via MFMA (64 same-type nodes / block) ----------------
__global__ __launch_bounds__(512, 2) void k1_mfma(const u16* __restrict__ xb,
        const u16* __restrict__ WallT,
        const void* __restrict__ bk, const void* __restrict__ bq,
        const void* __restrict__ bv,
        const int* __restrict__ lists, const int* __restrict__ cnts,
        const int* __restrict__ flag,
        u16* __restrict__ kb, u16* __restrict__ qb, u16* __restrict__ vb) {
    int f = *flag;
    int tt = blockIdx.x % TN, tile = blockIdx.x / TN;
    int cnt = cnts[tt];
    int start = tile * 64;
    if (start >= cnt) return;
    __shared__ int nl[64];
    __shared__ __align__(16) u16 xs[64][280];
    __shared__ __align__(16) float bias_s[768];
    int t = threadIdx.x;
    if (t < 64) nl[t] = (start + t < cnt) ? lists[tt * NN + start + t] : -1;
    if (t < 256) {
        bias_s[t]       = ld(bk, tt * 256 + t, f);
        bias_s[256 + t] = ld(bq, tt * 256 + t, f);
        bias_s[512 + t] = ld(bv, tt * 256 + t, f);
    }
    __syncthreads();
    {
        int i = t >> 4, g = t & 15;
        #pragma unroll
        for (int i2 = 0; i2 < 2; ++i2) {
            int row = i + i2 * 32;
            int node = nl[row];
            uint4 a = {0, 0, 0, 0}, b = {0, 0, 0, 0};
            if (node >= 0) {
                const uint4* src = (const uint4*)(xb + (size_t)node * 256 + g * 16);
                a = src[0]; b = src[1];
            }
            *(uint4*)&xs[row][g * 16] = a;
            *(uint4*)&xs[row][g * 16 + 8] = b;
        }
    }
    __syncthreads();
    int w = t >> 6, lane = t & 63, ln = lane & 15, quad = lane >> 4;
    const u16* Wt = WallT + (size_t)tt * 768 * 256;
    f32x4 acc[6][4];
    #pragma unroll
    for (int j = 0; j < 6; ++j)
        #pragma unroll
        for (int g = 0; g < 4; ++g)
            acc[j][g] = (f32x4){0.f, 0.f, 0.f, 0.f};
    for (int kt = 0; kt < 8; ++kt) {
        bf16x8 A[6];
        #pragma unroll
        for (int jt = 0; jt < 6; ++jt)
            A[jt] = *(const bf16x8*)(Wt + (size_t)(w * 96 + jt * 16 + ln) * 256 + kt * 32 + quad * 8);
        bf16x8 B[4];
        #pragma unroll
        for (int g = 0; g < 4; ++g)
            B[g] = *(const bf16x8*)&xs[g * 16 + ln][kt * 32 + quad * 8];
        #pragma unroll
        for (int jt = 0; jt < 6; ++jt)
            #pragma unroll
            for (int g = 0; g < 4; ++g)
                acc[jt][g] = __builtin_amdgcn_mfma_f32_16x16x32_bf16(A[jt], B[g], acc[jt][g], 0, 0, 0);
    }
    #pragma unroll
    for (int jt = 0; jt < 6; ++jt) {
        int jc = w * 96 + jt * 16 + quad * 4;
        float4 bi = *(const float4*)&bias_s[jc];
        int sec = jc >> 8, o = jc & 255;
        u16* basep = (sec == 0 ? kb : sec == 1 ? qb : vb);
        #pragma unroll
        for (int g = 0; g < 4; ++g) {
            int node = nl[g * 16 + ln];
            if (node >= 0) {
                ushort4 p;
                p.x = f2us(acc[jt][g][0] + bi.x); p.y = f2us(acc[jt][g][1] + bi.y);
                p.z = f2us(acc[jt][g][2] + bi.z); p.w = f2us(acc[jt][g][3] + bi.w);
                *(ushort4*)(basep + (size_t)node * 256 + o) = p;
            }
        }
    }
}

// ---------------- fused attention + aggregation, r-loop in block ----------------
// grid NN/CD = 3125; block = 16 consecutive dsts, loops r=0..5.
// sb2_[6][17] preloaded once. Per r: edge pass (half-wave owns dsts iA=w*2+half
// and iB=iA+8, INTERLEAVED: 4 row loads in flight; online softmax in regs)
// -> sync -> merged MFMA phase {accF += MTm[r]@sraw ; qrel(r+1)=MTa[r+1]@qL}
// -> sync. One tacc float4 store per dst at end. sorted[] holds src ids.
__global__ __launch_bounds__(256) void k2k4(const u16* __restrict__ kb,
        const u16* __restrict__ qb, const u16* __restrict__ vb,
        const u16* __restrict__ MTa, const u16* __restrict__ MTm,
        const void* __restrict__ rel_pri,
        const int* __restrict__ sorted, const int* __restrict__ base,
        const int* __restrict__ flag, float* __restrict__ tacc) {
    int f = *flag;
    int c0 = blockIdx.x * CD;
    int nd = min(CD, NN - c0);       // always 16 (50000 = 3125*16)
    __shared__ int sb2_[RN][CD + 1];
    __shared__ __align__(16) u16 qL[CD][264];
    __shared__ __align__(16) u16 qrelL[CD][264];
    __shared__ __align__(16) u16 srawL[CD][264];
    int t = threadIdx.x;
    int w = t >> 6, lane = t & 63, ln = lane & 15, quad = lane >> 4;
    int half = lane >> 5, lane32 = lane & 31;
    int hh = lane32 >> 3;            // head for the fused pass (8 lanes/head)
    // all 6 relations' segment bounds (102 entries)
    if (t < RN * (CD + 1)) {
        int rr = t / (CD + 1), ii = t % (CD + 1);
        sb2_[rr][ii] = base[rr * NN + c0 + ii];
    }
    // stage q rows ONCE (16 threads per row, 32B each)
    {
        int i = t >> 4, g = t & 15;
        uint4 a0 = {0,0,0,0}, a1 = {0,0,0,0};
        if (i < nd) {
            const uint4* src = (const uint4*)(qb + (size_t)(c0 + i) * 256 + g * 16);
            a0 = src[0]; a1 = src[1];
        }
        *(uint4*)&qL[i][g * 16] = a0;
        *(uint4*)&qL[i][g * 16 + 8] = a1;
    }
    f32x4 accF[4];
    #pragma unroll
    for (int m = 0; m < 4; ++m) accF[m] = (f32x4){0.f, 0.f, 0.f, 0.f};
    __syncthreads();   // qL + sb2 ready
    // prologue: qrel(0)
    {
        long mtbase = 0L * HN * 4096 + (long)w * 4096;
        bf16x8 B0 = *(const bf16x8*)&qL[ln][w * 64 + quad * 8];
        bf16x8 B1 = *(const bf16x8*)&qL[ln][w * 64 + quad * 8 + 32];
        #pragma unroll
        for (int mt = 0; mt < 4; ++mt) {
            const u16* ap = MTa + mtbase + (mt * 16 + ln) * 64 + quad * 8;
            bf16x8 A0 = *(const bf16x8*)(ap);
            bf16x8 A1 = *(const bf16x8*)(ap + 32);
            f32x4 acc = {0.f, 0.f, 0.f, 0.f};
            acc = __builtin_amdgcn_mfma_f32_16x16x32_bf16(A0, B0, acc, 0, 0, 0);
            acc = __builtin_amdgcn_mfma_f32_16x16x32_bf16(A1, B1, acc, 0, 0, 0);
            int jc = w * 64 + mt * 16 + quad * 4;
            ushort4 pq;
            pq.x = f2us(acc[0]); pq.y = f2us(acc[1]);
            pq.z = f2us(acc[2]); pq.w = f2us(acc[3]);
            *(ushort4*)&qrelL[ln][jc] = pq;
        }
    }
    __syncthreads();   // qrel(0) ready

    for (int r = 0; r < RN; ++r) {
        // ---- fused edge pass: dual-dst interleaved, online softmax ----
        {
            float pri = ld(rel_pri, r * HN + hh, f) * 0.125f;
            int iA = w * 2 + half;       // 0..7
            int iB = iA + 8;             // 8..15
            int sbA = sb2_[r][iA], nA = sb2_[r][iA + 1] - sbA;
            int sbB = sb2_[r][iB], nB = sb2_[r][iB + 1] - sbB;
            float aA0=0.f,aA1=0.f,aA2=0.f,aA3=0.f,aA4=0.f,aA5=0.f,aA6=0.f,aA7=0.f;
            float aB0=0.f,aB1=0.f,aB2=0.f,aB3=0.f,aB4=0.f,aB5=0.f,aB6=0.f,aB7=0.f;
            float denA = 0.f, denB = 0.f;
            uint4 qvA = *(const uint4*)&qrelL[iA][lane32 * 8];
            uint4 qvB = *(const uint4*)&qrelL[iB][lane32 * 8];
            int nmax = max(nA, nB);
            for (int j = 0; j < nmax; ++j) {
                // issue all row loads first (up to 4 x 16B in flight)
                uint4 kvA, vvA, kvB, vvB;
                bool doA = (j < nA), doB = (j < nB);
                int sA = doA ? sorted[sbA + j] : 0;
                int sB = doB ? sorted[sbB + j] : 0;
                size_t roA = (size_t)sA * 256 + lane32 * 8;
                size_t roB = (size_t)sB * 256 + lane32 * 8;
                if (doA) { kvA = *(const uint4*)(kb + roA); vvA = *(const uint4*)(vb + roA); }
                if (doB) { kvB = *(const uint4*)(kb + roB); vvB = *(const uint4*)(vb + roB); }
                if (doA) {
                    float d = blo(kvA.x)*blo(qvA.x) + bhi(kvA.x)*bhi(qvA.x)
                            + blo(kvA.y)*blo(qvA.y) + bhi(kvA.y)*bhi(qvA.y)
                            + blo(kvA.z)*blo(qvA.z) + bhi(kvA.z)*bhi(qvA.z)
                            + blo(kvA.w)*blo(qvA.w) + bhi(kvA.w)*bhi(qvA.w);
                    d += __shfl_xor(d, 1); d += __shfl_xor(d, 2); d += __shfl_xor(d, 4);
                    float attv = fminf(fmaxf(d * pri, -50.f), 50.f);
                    float ex = expf(attv);
                    denA += ex;
                    aA0 += ex * blo(vvA.x); aA1 += ex * bhi(vvA.x);
                    aA2 += ex * blo(vvA.y); aA3 += ex * bhi(vvA.y);
                    aA4 += ex * blo(vvA.z); aA5 += ex * bhi(vvA.z);
                    aA6 += ex * blo(vvA.w); aA7 += ex * bhi(vvA.w);
                }
                if (doB) {
                    float d = blo(kvB.x)*blo(qvB.x) + bhi(kvB.x)*bhi(qvB.x)
                            + blo(kvB.y)*blo(qvB.y) + bhi(kvB.y)*bhi(qvB.y)
                            + blo(kvB.z)*blo(qvB.z) + bhi(kvB.z)*bhi(qvB.z)
                            + blo(kvB.w)*blo(qvB.w) + bhi(kvB.w)*bhi(qvB.w);
                    d += __shfl_xor(d, 1); d += __shfl_xor(d, 2); d += __shfl_xor(d, 4);
                    float attv = fminf(fmaxf(d * pri, -50.f), 50.f);
                    float ex = expf(attv);
                    denB += ex;
                    aB0 += ex * blo(vvB.x); aB1 += ex * bhi(vvB.x);
                    aB2 += ex * blo(vvB.y); aB3 += ex * bhi(vvB.y);
                    aB4 += ex * blo(vvB.z); aB5 += ex * bhi(vvB.z);
                    aB6 += ex * blo(vvB.w); aB7 += ex * bhi(vvB.w);
                }
            }
            {
                float inv = (nA > 0) ? 1.f / denA : 0.f;
                u16 pv8[8];
                pv8[0]=f2us(aA0*inv); pv8[1]=f2us(aA1*inv); pv8[2]=f2us(aA2*inv); pv8[3]=f2us(aA3*inv);
                pv8[4]=f2us(aA4*inv); pv8[5]=f2us(aA5*inv); pv8[6]=f2us(aA6*inv); pv8[7]=f2us(aA7*inv);
                *(uint4*)&srawL[iA][lane32 * 8] = *(const uint4*)pv8;
            }
            {
                float inv = (nB > 0) ? 1.f / denB : 0.f;
                u16 pv8[8];
                pv8[0]=f2us(aB0*inv); pv8[1]=f2us(aB1*inv); pv8[2]=f2us(aB2*inv); pv8[3]=f2us(aB3*inv);
                pv8[4]=f2us(aB4*inv); pv8[5]=f2us(aB5*inv); pv8[6]=f2us(aB6*inv); pv8[7]=f2us(aB7*inv);
                *(uint4*)&srawL[iB][lane32 * 8] = *(const uint4*)pv8;
            }
        }
        __syncthreads();   // sraw(r) ready; qrelL dead
        // ---- merged MFMA phase: accF += MTm[r] @ sraw ; qrel(r+1) ----
        {
            long mtbase = (long)(r * HN + w) * 4096;
            bf16x8 B0 = *(const bf16x8*)&srawL[ln][w * 64 + quad * 8];
            bf16x8 B1 = *(const bf16x8*)&srawL[ln][w * 64 + quad * 8 + 32];
            #pragma unroll
            for (int mt = 0; mt < 4; ++mt) {
                const u16* mp = MTm + mtbase + (mt * 16 + ln) * 64 + quad * 8;
                bf16x8 A0 = *(const bf16x8*)(mp);
                bf16x8 A1 = *(const bf16x8*)(mp + 32);
                accF[mt] = __builtin_amdgcn_mfma_f32_16x16x32_bf16(A0, B0, accF[mt], 0, 0, 0);
                accF[mt] = __builtin_amdgcn_mfma_f32_16x16x32_bf16(A1, B1, accF[mt], 0, 0, 0);
            }
            if (r + 1 < RN) {
                long mtbase2 = (long)((r + 1) * HN + w) * 4096;
                bf16x8 Q0 = *(const bf16x8*)&qL[ln][w * 64 + quad * 8];
                bf16x8 Q1 = *(const bf16x8*)&qL[ln][w * 64 + quad * 8 + 32];
                #pragma unroll
                for (int mt = 0; mt < 4; ++mt) {
                    const u16* ap = MTa + mtbase2 + (mt * 16 + ln) * 64 + quad * 8;
                    bf16x8 A0 = *(const bf16x8*)(ap);
                    bf16x8 A1 = *(const bf16x8*)(ap + 32);
                    f32x4 acc = {0.f, 0.f, 0.f, 0.f};
                    acc = __builtin_amdgcn_mfma_f32_16x16x32_bf16(A0, Q0, acc, 0, 0, 0);
                    acc = __builtin_amdgcn_mfma_f32_16x16x32_bf16(A1, Q1, acc, 0, 0, 0);
                    int jc = w * 64 + mt * 16 + quad * 4;
                    ushort4 pq;
                    pq.x = f2us(acc[0]); pq.y = f2us(acc[1]);
                    pq.z = f2us(acc[2]); pq.w = f2us(acc[3]);
                    *(ushort4*)&qrelL[ln][jc] = pq;
                }
            }
        }
        __syncthreads();   // accF consumed sraw; qrel(r+1) ready
    }
    // single tacc write (f32, no atomics)
    if (ln < nd) {
        #pragma unroll
        for (int mt = 0; mt < 4; ++mt) {
            int jc = w * 64 + mt * 16 + quad * 4;
            float4 v = {accF[mt][0], accF[mt][1], accF[mt][2], accF[mt][3]};
            *(float4*)(tacc + (long)(c0 + ln) * 256 + jc) = v;
        }
    }
}

// ---------------- fused out-linear (MFMA) + skip-gate + LayerNorm ----------------
__global__ __launch_bounds__(512, 4) void k5_fused(const void* __restrict__ x,
        const float* __restrict__ tacc, const u16* __restrict__ WaT,
        const void* __restrict__ ba, const void* __restrict__ skip,
        const void* __restrict__ ln_g, const void* __restrict__ ln_b,
        const int* __restrict__ base,
        const int* __restrict__ lists, const int* __restrict__ cnts,
        const int* __restrict__ flag, void* out) {
    int f = *flag;
    int tt = blockIdx.x % TN, tile = blockIdx.x / TN;
    int cnt = cnts[tt];
    int start = tile * 64;
    if (start >= cnt) return;
    __shared__ int nl[64];
    __shared__ float invs[64];
    __shared__ int hasv[64];
    __shared__ __align__(16) u16 xs[64][280];
    __shared__ __align__(16) float ba_s[256], lnG_s[256], lnB_s[256];
    __shared__ float red1[64][8], red2[64][8];
    __shared__ float mu_[64], rs_[64];
    int t = threadIdx.x;
    if (t < 64) {
        int node = (start + t < cnt) ? lists[tt * NN + start + t] : -1;
        nl[t] = node;
        int nrel = 0;
        if (node >= 0) {
            #pragma unroll
            for (int r = 0; r < RN; ++r)
                nrel += (base[r * NN + node + 1] > base[r * NN + node]) ? 1 : 0;
        }
        hasv[t] = nrel;
        invs[t] = (nrel > 0) ? 1.f / (float)nrel : 1.f;
    }
    if (t < 256) {
        ba_s[t]  = ld(ba,   tt * 256 + t, f);
        lnG_s[t] = ld(ln_g, tt * 256 + t, f);
        lnB_s[t] = ld(ln_b, tt * 256 + t, f);
    }
    __syncthreads();
    // gather tacc (f32) -> xs (bf16, pre-divided by nrel), vectorized
    {
        int i = t >> 3, g8 = t & 7;
        int node = nl[i];
        float inv = invs[i];
        int o0 = g8 * 32;
        u16 tmp[32];
        if (node >= 0) {
            const float* src = tacc + (long)node * 256 + o0;
            #pragma unroll
            for (int j = 0; j < 8; ++j) {
                float4 v = *(const float4*)(src + j * 4);
                tmp[j*4+0] = f2us(v.x * inv); tmp[j*4+1] = f2us(v.y * inv);
                tmp[j*4+2] = f2us(v.z * inv); tmp[j*4+3] = f2us(v.w * inv);
            }
        } else {
            #pragma unroll
            for (int j = 0; j < 32; ++j) tmp[j] = 0;
        }
        #pragma unroll
        for (int j = 0; j < 4; ++j)
            *(uint4*)&xs[i][o0 + j * 8] = ((const uint4*)tmp)[j];
    }
    __syncthreads();
    int w = t >> 6, lane = t & 63, ln = lane & 15, quad = lane >> 4;
    const u16* Wt = WaT + (size_t)tt * 65536;
    f32x4 acc[2][4];
    #pragma unroll
    for (int j = 0; j < 2; ++j)
        #pragma unroll
        for (int g = 0; g < 4; ++g)
            acc[j][g] = (f32x4){0.f, 0.f, 0.f, 0.f};
    for (int kt = 0; kt < 8; ++kt) {
        bf16x8 A[2];
        #pragma unroll
        for (int jt = 0; jt < 2; ++jt)
            A[jt] = *(const bf16x8*)(Wt + (size_t)(w * 32 + jt * 16 + ln) * 256 + kt * 32 + quad * 8);
        bf16x8 B[4];
        #pragma unroll
        for (int g = 0; g < 4; ++g)
            B[g] = *(const bf16x8*)&xs[g * 16 + ln][kt * 32 + quad * 8];
        #pragma unroll
        for (int jt = 0; jt < 2; ++jt)
            #pragma unroll
            for (int g = 0; g < 4; ++g)
                acc[jt][g] = __builtin_amdgcn_mfma_f32_16x16x32_bf16(A[jt], B[g], acc[jt][g], 0, 0, 0);
    }
    float sk = ld(skip, tt, f);
    float alpha = 1.f / (1.f + expf(-sk));
    float p1[4] = {0.f, 0.f, 0.f, 0.f}, p2[4] = {0.f, 0.f, 0.f, 0.f};
    #pragma unroll
    for (int g = 0; g < 4; ++g) {
        int node = nl[g * 16 + ln];
        if (node < 0) continue;
        #pragma unroll
        for (int jt = 0; jt < 2; ++jt) {
            int jc = w * 32 + jt * 16 + quad * 4;
            float4 bi = *(const float4*)&ba_s[jc];
            long xo = (long)node * 256 + jc;
            float xv[4];
            if (f) {
                float4 v = *(const float4*)((const float*)x + xo);
                xv[0] = v.x; xv[1] = v.y; xv[2] = v.z; xv[3] = v.w;
            } else {
                ushort4 v = *(const ushort4*)((const u16*)x + xo);
                xv[0] = busf(v.x); xv[1] = busf(v.y); xv[2] = busf(v.z); xv[3] = busf(v.w);
            }
            #pragma unroll
            for (int rg = 0; rg < 4; ++rg) {
                float ov = acc[jt][g][rg] + ((const float*)&bi)[rg];
                ov = ov * alpha + xv[rg] * (1.f - alpha);
                acc[jt][g][rg] = ov;
                p1[g] += ov; p2[g] += ov * ov;
            }
        }
    }
    #pragma unroll
    for (int g = 0; g < 4; ++g) {
        p1[g] += __shfl_xor(p1[g], 16); p1[g] += __shfl_xor(p1[g], 32);
        p2[g] += __shfl_xor(p2[g], 16); p2[g] += __shfl_xor(p2[g], 32);
    }
    if (quad == 0) {
        #pragma unroll
        for (int g = 0; g < 4; ++g) {
            red1[g * 16 + ln][w] = p1[g];
            red2[g * 16 + ln][w] = p2[g];
        }
    }
    __syncthreads();
    if (t < 64) {
        float s1 = 0.f, s2 = 0.f;
        #pragma unroll
        for (int j = 0; j < 8; ++j) { s1 += red1[t][j]; s2 += red2[t][j]; }
        float mu = s1 * (1.f / 256.f);
        float ms = s2 * (1.f / 256.f);
        float var = fmaxf(ms - mu * mu, 0.f);
        mu_[t] = mu; rs_[t] = rsqrtf(var + 1e-5f);
    }
    __syncthreads();
    #pragma unroll
    for (int g = 0; g < 4; ++g) {
        int li = g * 16 + ln;
        int node = nl[li];
        if (node < 0) continue;
        if (hasv[li] > 0) {
            float mu = mu_[li], rs = rs_[li];
            #pragma unroll
            for (int jt = 0; jt < 2; ++jt) {
                int jc = w * 32 + jt * 16 + quad * 4;
                float4 gg = *(const float4*)&lnG_s[jc];
                float4 bb = *(const float4*)&lnB_s[jc];
                long oo = (long)node * 256 + jc;
                float r0 = (acc[jt][g][0] - mu) * rs * gg.x + bb.x;
                float r1 = (acc[jt][g][1] - mu) * rs * gg.y + bb.y;
                float r2 = (acc[jt][g][2] - mu) * rs * gg.z + bb.z;
                float r3 = (acc[jt][g][3] - mu) * rs * gg.w + bb.w;
                if (f) { float4 v = {r0, r1, r2, r3}; *(float4*)((float*)out + oo) = v; }
                else   { ushort4 v; v.x = f2us(r0); v.y = f2us(r1); v.z = f2us(r2); v.w = f2us(r3);
                         *(ushort4*)((u16*)out + oo) = v; }
            }
        } else {
            #pragma unroll
            for (int jt = 0; jt < 2; ++jt) {
                int jc = w * 32 + jt * 16 + quad * 4;
                long oo = (long)node * 256 + jc;
                if (f) { *(float4*)((float*)out + oo) = *(const float4*)((const float*)x + oo); }
                else   { *(ushort4*)((u16*)out + oo) = *(const ushort4*)((const u16*)x + oo); }
            }
        }
    }
}

extern "C" void kernel_launch(void* const* d_in, const int* in_sizes, int n_in,
                              void* d_out, int out_size, void* d_ws, size_t ws_size,
                              hipStream_t stream) {
    const void* x       = d_in[0];
    const void* Wk      = d_in[1];
    const void* bk      = d_in[2];
    const void* Wq      = d_in[3];
    const void* bq      = d_in[4];
    const void* Wv      = d_in[5];
    const void* bv      = d_in[6];
    const void* Wa      = d_in[7];
    const void* ba      = d_in[8];
    const void* rel_pri = d_in[9];
    const void* rel_att = d_in[10];
    const void* rel_msg = d_in[11];
    const void* skip    = d_in[12];
    const void* ln_g    = d_in[13];
    const void* ln_b    = d_in[14];
    const int* node_type = (const int*)d_in[15];
    const int* edge_src  = (const int*)d_in[16];
    const int* edge_dst  = (const int*)d_in[17];
    const int* edge_type = (const int*)d_in[18];
    char* w = (char*)d_ws;

    // layout (bytes) — total 137,767,552 <= proven ws floor 141,000,128
    u16*      kb     = (u16*)(w);                    // 25,600,000
    u16*      qb     = (u16*)(w + 25600000);         // 25,600,000
    u16*      vb     = (u16*)(w + 51200000);         // 25,600,000
    float*    tacc   = (float*)(w + 76800000);       // 51,200,000 (f32; xb overlay first)
    u16*      xb     = (u16*)(w + 76800000);         //   overlay (consumed by k1)
    u16*      attex  = (u16*)(w + 128000000);        //  3,200,000 (unused since R14)
    int*      sorted = (int*)(w + 131200000);        //  1,600,000 (holds SRC ids)
    int*      base   = (int*)(w + 132800000);        //  1,200,064
    int*      nlists = (int*)(w + 134000064);        //    600,000
    u16*      MTa    = (u16*)(w + 134600064);        //    196,608
    u16*      MTm    = (u16*)(w + 134796672);        //    196,608
    u16*      WallT  = (u16*)(w + 134993280);        //  1,179,648
    u16*      WaT    = (u16*)(w + 136172928);        //    393,216
    // zero region:
    unsigned* cnt    = (unsigned*)(w + 136566144);   //  1,200,000
    int*      ncnts  = (int*)(w + 137766144);        //         64
    int*      flag   = (int*)(w + 137766208);        //         64
    unsigned* csums  = (unsigned*)(w + 137766272);   //      1,280
    (void)attex;

    hipMemsetAsync(w + 136566144, 0, 1201408, stream);

    detect_dtype<<<dim3(1), dim3(256), 0, stream>>>(x, flag);
    prep<<<dim3(17379), dim3(256), 0, stream>>>(
        rel_att, rel_msg, Wk, Wq, Wv, Wa, x, node_type, edge_dst, edge_type,
        flag, MTa, MTm, WallT, WaT, xb, nlists, ncnts, cnt);
    scanA<<<dim3(NCHUNK), dim3(256), 0, stream>>>(cnt, csums);
    scanB<<<dim3(1), dim3(256), 0, stream>>>(csums, base);
    scanC<<<dim3(NCHUNK), dim3(256), 0, stream>>>(cnt, csums, base);
    scatter_edges<<<dim3((EE + 255) / 256), dim3(256), 0, stream>>>(
        edge_dst, edge_type, edge_src, base, cnt, sorted);

    k1_mfma<<<dim3(TN * ((NN + 63) / 64)), dim3(512), 0, stream>>>(
        xb, WallT, bk, bq, bv, nlists, ncnts, flag, kb, qb, vb);

    // tacc fully overwritten by k2k4 (register accumulation) -> no memset

    k2k4<<<dim3(NN / CD), dim3(256), 0, stream>>>(
        kb, qb, vb, MTa, MTm, rel_pri, sorted, base, flag, tacc);

    k5_fused<<<dim3(TN * ((NN + 63) / 64)), dim3(512), 0, stream>>>(
        x, tacc, WaT, ba, skip, ln_g, ln_b, base, nlists, ncnts, flag, d_out);
}